// Round 1
// baseline (1147.069 us; speedup 1.0000x reference)
//
#include <hip/hip_runtime.h>
#include <cstddef>
#include <cstdint>

#define B_ 16
#define N_ 1024
#define CIN_ 256
#define MID_ 512
#define OUT_ 256

__device__ __forceinline__ float sigf(float z){ return 1.f/(1.f+expf(-z)); }

// ---------- lj / li ----------
__global__ __launch_bounds__(256) void k_prep(const float* __restrict__ x,
    const float* __restrict__ Watt, float* __restrict__ lj, float* __restrict__ li)
{
  int bn = blockIdx.x*256 + threadIdx.x;           // 0..16383
  const float4* xr = (const float4*)(x + (size_t)bn*CIN_);
  const float4* wq = (const float4*)(Watt);
  const float4* wk = (const float4*)(Watt + CIN_);
  float aq=0.f, ak=0.f;
  #pragma unroll 8
  for(int c=0;c<CIN_/4;++c){
    float4 xv=xr[c]; float4 q=wq[c]; float4 w=wk[c];
    aq += xv.x*q.x+xv.y*q.y+xv.z*q.z+xv.w*q.w;
    ak += xv.x*w.x+xv.y*w.y+xv.z*w.z+xv.w*w.w;
  }
  lj[bn]=aq; li[bn]=ak;
}

// ---------- Wg transpose ----------
__global__ __launch_bounds__(256) void k_wgt(const float* __restrict__ Wg, float* __restrict__ WgT){
  int o=blockIdx.x, c=threadIdx.x;
  WgT[(size_t)o*CIN_ + c] = Wg[(size_t)c*OUT_ + o];
}

// ---------- col union (exact top_k membership) ----------
__global__ __launch_bounds__(256) void k_col(
    const float* __restrict__ m1, const float* __restrict__ m2,
    const float* __restrict__ sc, const float* __restrict__ lj,
    const float* __restrict__ li, const float* __restrict__ batt,
    float* __restrict__ colf)
{
  int row = blockIdx.x; int b = row >> 10; int t = threadIdx.x;
  size_t base = (size_t)row*N_ + 4*t;
  float4 m1v = *(const float4*)(m1 + base);
  float4 m2v = *(const float4*)(m2 + base);
  float4 scv = *(const float4*)(sc + (b<<10) + 4*t);
  float mr1[4] = {m1v.x*scv.x, m1v.y*scv.y, m1v.z*scv.z, m1v.w*scv.w};
  float mr2[4] = {m2v.x*scv.x, m2v.y*scv.y, m2v.z*scv.z, m2v.w*scv.w};
  int z1=0,z2=0;
  #pragma unroll
  for(int k=0;k<4;++k){ z1 += (mr1[k]==0.f); z2 += (mr2[k]==0.f); }
  __shared__ int sc1[256], sc2[256];
  __shared__ float A1s[1024], A2s[1024];
  sc1[t]=z1; sc2[t]=z2; __syncthreads();
  for(int off=1; off<256; off<<=1){
    int a=0,c=0;
    if(t>=off){ a=sc1[t-off]; c=sc2[t-off]; }
    __syncthreads();
    if(t>=off){ sc1[t]+=a; sc2[t]+=c; }
    __syncthreads();
  }
  int excl1 = sc1[t]-z1, excl2 = sc2[t]-z2;
  int Z1 = sc1[255], Z2 = sc2[255];
  int P1 = 1024-Z1, P2 = 1024-Z2;
  bool rare = (P1>128)||(P2>256)||(Z1<128)||(Z2<128);
  if(!rare){
    int zb1=excl1, zb2=excl2;
    #pragma unroll
    for(int k=0;k<4;++k){
      // positives always qualify (P1<=128 / P2<=256); zeros by zero-index rank
      bool q = (mr1[k]!=0.f) || (zb1<128) || (mr2[k]!=0.f) || (zb2<128) || (P2+zb2<256);
      if(q) colf[4*t+k]=1.0f;
      zb1 += (mr1[k]==0.f); zb2 += (mr2[k]==0.f);
    }
  } else {
    float lir = li[row], ba = batt[0];
    float4 ljv = *(const float4*)(lj + (b<<10) + 4*t);
    float ljr[4]={ljv.x,ljv.y,ljv.z,ljv.w};
    #pragma unroll
    for(int k=0;k<4;++k){
      float v = sigf(ljr[k]+lir+ba);
      A1s[4*t+k]=mr1[k]*v; A2s[4*t+k]=mr2[k]*v;
    }
    __syncthreads();
    for(int k=0;k<4;++k){
      int j=4*t+k; float a1j=A1s[j], a2j=A2s[j];
      int r1=0,r1m=0,r2=0,r2m=0;
      for(int jp=0;jp<1024;++jp){
        float p1=A1s[jp], p2=A2s[jp];
        bool lo = jp<j;
        r1  += (p1>a1j)||((p1==a1j)&&lo);
        r1m += (p1<a1j)||((p1==a1j)&&lo);
        r2  += (p2>a2j)||((p2==a2j)&&lo);
        r2m += (p2<a2j)||((p2==a2j)&&lo);
      }
      if(r1<128||r1m<128||r2<256||r2m<128) colf[j]=1.0f;
    }
  }
}

// ---------- At matrix ----------
__global__ __launch_bounds__(256) void k_at(const float* __restrict__ m1,
    const float* __restrict__ m2, const float* __restrict__ sc,
    const float* __restrict__ lj, const float* __restrict__ li,
    const float* __restrict__ batt, const float* __restrict__ colf,
    float* __restrict__ At)
{
  int row=blockIdx.x, t=threadIdx.x; int b=row>>10, i=row&1023;
  size_t base=(size_t)row*N_ + 4*t;
  float4 m1v=*(const float4*)(m1+base);
  float4 m2v=*(const float4*)(m2+base);
  float4 scv=*(const float4*)(sc + (b<<10) + 4*t);
  float4 ljv=*(const float4*)(lj + (b<<10) + 4*t);
  float4 cv =*(const float4*)(colf + 4*t);
  float lir=li[row], ba=batt[0];
  float fi = (sc[(b<<10)+i]==0.f)?1.f:0.f;
  float mra[4]={(m1v.x+m2v.x)*scv.x,(m1v.y+m2v.y)*scv.y,(m1v.z+m2v.z)*scv.z,(m1v.w+m2v.w)*scv.w};
  float ljr[4]={ljv.x,ljv.y,ljv.z,ljv.w};
  float cr[4]={cv.x,cv.y,cv.z,cv.w};
  float o[4]; int j0=4*t;
  #pragma unroll
  for(int k=0;k<4;++k){
    float v=sigf(ljr[k]+lir+ba);
    float val=v*mra[k]*cr[k];
    if(j0+k==i) val+=fi;
    o[k]=val*(1.f/512.f);
  }
  *(float4*)(At+base) = make_float4(o[0],o[1],o[2],o[3]);
}

// ---------- generic NT GEMM: C[i][m] = sum_k A[i][k]*B[m][k] ----------
template<int BM,int BN,int TM,int TN>
__global__ __launch_bounds__(256) void gemm_nt(
    const float* __restrict__ A, int lda, long long sAb, long long sAg,
    const float* __restrict__ Bp, int ldb, long long sBb, long long sBg,
    float* __restrict__ C, int ldc, long long sCb, long long sCg,
    int K, int nG,
    const float* __restrict__ biasM, int biasMG,
    const float* __restrict__ biasN, int relu)
{
  static_assert(TN==4 && BM/TM==16 && BN/TN==16, "layout");
  constexpr int BK=32, LDSS=BK+4;
  int z=blockIdx.z, b=z/nG, g=z%nG;
  A  += b*sAb + g*sAg;
  Bp += b*sBb + g*sBg;
  C  += b*sCb + g*sCg;
  __shared__ float As[BM*LDSS];
  __shared__ float Bs[BN*LDSS];
  int tid=threadIdx.x;
  int tx=tid&15, ty=tid>>4;
  int m0=blockIdx.y*BM, n0=blockIdx.x*BN;
  float acc[TM][TN]={};
  for(int k0=0;k0<K;k0+=BK){
    #pragma unroll
    for(int u=0;u<BM*BK/1024;++u){
      int f=u*256+tid, r=f>>3, c=(f&7)*4;
      *(float4*)&As[r*LDSS+c] = *(const float4*)(A + (size_t)(m0+r)*lda + k0 + c);
    }
    #pragma unroll
    for(int u=0;u<BN*BK/1024;++u){
      int f=u*256+tid, r=f>>3, c=(f&7)*4;
      *(float4*)&Bs[r*LDSS+c] = *(const float4*)(Bp + (size_t)(n0+r)*ldb + k0 + c);
    }
    __syncthreads();
    #pragma unroll
    for(int kk=0;kk<BK;kk+=4){
      float4 av[TM]; float4 bv[TN];
      #pragma unroll
      for(int r=0;r<TM;++r) av[r]=*(const float4*)&As[(ty*TM+r)*LDSS+kk];
      #pragma unroll
      for(int c=0;c<TN;++c) bv[c]=*(const float4*)&Bs[(tx*TN+c)*LDSS+kk];
      #pragma unroll
      for(int r=0;r<TM;++r){
        #pragma unroll
        for(int c=0;c<TN;++c){
          acc[r][c] += av[r].x*bv[c].x + av[r].y*bv[c].y + av[r].z*bv[c].z + av[r].w*bv[c].w;
        }
      }
    }
    __syncthreads();
  }
  float4 bnv=make_float4(0.f,0.f,0.f,0.f);
  if(biasN){ bnv=*(const float4*)(biasN + n0 + tx*TN); }
  #pragma unroll
  for(int r=0;r<TM;++r){
    int m=m0+ty*TM+r;
    float bm = biasM ? biasM[(size_t)g*biasMG + m] : 0.f;
    float4 v;
    v.x=acc[r][0]+bm+bnv.x;
    v.y=acc[r][1]+bm+bnv.y;
    v.z=acc[r][2]+bm+bnv.z;
    v.w=acc[r][3]+bm+bnv.w;
    if(relu){ v.x=fmaxf(v.x,0.f); v.y=fmaxf(v.y,0.f); v.z=fmaxf(v.z,0.f); v.w=fmaxf(v.w,0.f); }
    *(float4*)(C + (size_t)m*ldc + n0 + tx*TN) = v;
  }
}

// ---------- LN1 + residual (in-place on o1mT -> o1pT) ----------
__global__ __launch_bounds__(256) void k_ln1(const float* o1mT, const float* o1,
    const float* __restrict__ g1v, const float* __restrict__ be1, float* o1pT)
{
  int row=blockIdx.x, t=threadIdx.x; int b=row>>10, i=row&1023;
  float2 v = ((const float2*)(o1mT + (size_t)row*MID_))[t];
  float s=v.x+v.y, s2=v.x*v.x+v.y*v.y;
  for(int off=32; off; off>>=1){ s+=__shfl_down(s,off); s2+=__shfl_down(s2,off); }
  __shared__ float sm[8];
  int lane=t&63, wid=t>>6;
  if(lane==0){ sm[wid]=s; sm[4+wid]=s2; }
  __syncthreads();
  s=sm[0]+sm[1]+sm[2]+sm[3]; s2=sm[4]+sm[5]+sm[6]+sm[7];
  float mean=s*(1.f/MID_), var=s2*(1.f/MID_)-mean*mean;
  float rstd=rsqrtf(var+1e-6f);
  int m0=2*t;
  float a0=(v.x-mean)*rstd*g1v[m0]+be1[m0];
  float a1=(v.y-mean)*rstd*g1v[m0+1]+be1[m0+1];
  float2 o;
  o.x = a0 + o1[((size_t)(b*MID_+m0  ))*N_ + i];
  o.y = a1 + o1[((size_t)(b*MID_+m0+1))*N_ + i];
  ((float2*)(o1pT + (size_t)row*MID_))[t] = o;
}

// ---------- LN2 + final outputs ----------
__global__ __launch_bounds__(256) void k_ln2f(const float* o2mT, const float* o2,
    const float* __restrict__ g2v, const float* __restrict__ be2,
    float* node, float* out2)
{
  int row=blockIdx.x, t=threadIdx.x; int b=row>>10, i=row&1023;
  float v = o2mT[(size_t)row*OUT_ + t];
  float s=v, s2=v*v;
  for(int off=32; off; off>>=1){ s+=__shfl_down(s,off); s2+=__shfl_down(s2,off); }
  __shared__ float sm[8];
  int lane=t&63, wid=t>>6;
  if(lane==0){ sm[wid]=s; sm[4+wid]=s2; }
  __syncthreads();
  s=sm[0]+sm[1]+sm[2]+sm[3]; s2=sm[4]+sm[5]+sm[6]+sm[7];
  float mean=s*(1.f/OUT_); float var=s2*(1.f/OUT_)-mean*mean;
  float rstd=rsqrtf(var+1e-6f);
  float nf=(v-mean)*rstd*g2v[t]+be2[t];
  size_t ro=(size_t)row*OUT_+t;
  node[ro]=nf;
  out2[ro]=nf + o2[((size_t)(b*OUT_+t))*N_ + i];
}

extern "C" void kernel_launch(void* const* d_in, const int* in_sizes, int n_in,
                              void* d_out, int out_size, void* d_ws, size_t ws_size,
                              hipStream_t stream)
{
  const float* x    = (const float*)d_in[0];
  const float* m1   = (const float*)d_in[1];
  const float* m2   = (const float*)d_in[2];
  const float* sc   = (const float*)d_in[3];
  const float* gt   = (const float*)d_in[4];
  const float* Watt = (const float*)d_in[5];
  const float* batt = (const float*)d_in[6];
  const float* W1   = (const float*)d_in[7];
  const float* b1   = (const float*)d_in[8];
  const float* W2   = (const float*)d_in[9];
  const float* b2   = (const float*)d_in[10];
  const float* g1   = (const float*)d_in[11];
  const float* be1  = (const float*)d_in[12];
  const float* g2   = (const float*)d_in[13];
  const float* be2  = (const float*)d_in[14];
  const float* Wg   = (const float*)d_in[15];
  const float* bg   = (const float*)d_in[16];

  float* out2 = (float*)d_out;
  float* gtso = out2 + (size_t)B_*N_*OUT_;
  float* node = gtso + (size_t)B_*N_*OUT_;

  char* ws = (char*)d_ws;
  float* colf = (float*)(ws);                                   // 4 KB
  float* lj   = (float*)(ws + 4096);                            // 64 KB
  float* li   = (float*)(ws + 4096 + 65536);                    // 64 KB
  float* WgT  = (float*)(ws + 4096 + 131072);                   // 256 KB
  float* At   = (float*)(ws + 397312);                          // 64 MB
  float* o1   = (float*)(ws + 397312 + 67108864);               // 32 MB
  float* o1mT = (float*)(ws + 397312 + 67108864 + 33554432);    // 32 MB
  float* o1pT = o1mT;   // LN1 is per-element in-place safe
  float* o2   = o1;     // o1 dead after LN1
  float* o2mT = o1mT;   // o1pT dead after gconv2

  hipMemsetAsync(colf, 0, 4096, stream);
  k_prep<<<dim3(B_*N_/256),dim3(256),0,stream>>>(x,Watt,lj,li);
  k_wgt <<<dim3(OUT_),dim3(256),0,stream>>>(Wg,WgT);
  k_col <<<dim3(B_*N_),dim3(256),0,stream>>>(m1,m2,sc,lj,li,batt,colf);
  k_at  <<<dim3(B_*N_),dim3(256),0,stream>>>(m1,m2,sc,lj,li,batt,colf,At);

  // gts = relu(gt_feat @ Wg + bg): C[n(16384)][o(256)]
  gemm_nt<128,64,8,4><<<dim3(OUT_/64, (B_*N_)/128, 1),256,0,stream>>>(
      gt, CIN_, 0,0,
      WgT, CIN_, 0,0,
      gtso, OUT_, 0,0,
      CIN_, 1, nullptr,0, bg, 1);

  // gconv1: per (b,g): o1[b,128g+m',n] = relu(W1g . x)
  gemm_nt<64,64,4,4><<<dim3(N_/64, 2, B_*4),256,0,stream>>>(
      W1, 64, 0, (long long)128*64,
      x, CIN_, (long long)N_*CIN_, 64,
      o1, N_, (long long)MID_*N_, (long long)128*N_,
      64, 4, b1, 128, nullptr, 1);

  // GEMM1: o1mT[b,i,m] = sum_j At[b,i,j]*o1[b,m,j]
  gemm_nt<128,64,8,4><<<dim3(MID_/64, N_/128, B_),256,0,stream>>>(
      At, N_, (long long)N_*N_, 0,
      o1, N_, (long long)MID_*N_, 0,
      o1mT, MID_, (long long)N_*MID_, 0,
      N_, 1, nullptr,0, nullptr, 0);

  k_ln1<<<dim3(B_*N_),256,0,stream>>>(o1mT, o1, g1, be1, o1pT);

  // gconv2: per (b,g): o2[b,64g+m',n] = relu(W2g . o1')
  gemm_nt<64,64,4,4><<<dim3(N_/64, 1, B_*4),256,0,stream>>>(
      W2, 128, 0, (long long)64*128,
      o1pT, MID_, (long long)N_*MID_, 128,
      o2, N_, (long long)OUT_*N_, (long long)64*N_,
      128, 4, b2, 64, nullptr, 1);

  // GEMM2: o2mT[b,i,m] = sum_j At[b,i,j]*o2[b,m,j]
  gemm_nt<128,64,8,4><<<dim3(OUT_/64, N_/128, B_),256,0,stream>>>(
      At, N_, (long long)N_*N_, 0,
      o2, N_, (long long)OUT_*N_, 0,
      o2mT, OUT_, (long long)N_*OUT_, 0,
      N_, 1, nullptr,0, nullptr, 0);

  k_ln2f<<<dim3(B_*N_),256,0,stream>>>(o2mT, o2, g2, be2, node, out2);
}

// Round 2
// 468.343 us; speedup vs baseline: 2.4492x; 2.4492x over previous
//
#include <hip/hip_runtime.h>
#include <cstddef>
#include <cstdint>

#define B_ 16
#define N_ 1024
#define CIN_ 256
#define MID_ 512
#define OUT_ 256

typedef __attribute__((ext_vector_type(8))) short short8v;
typedef __attribute__((ext_vector_type(4))) float f32x4;

__device__ __forceinline__ float sigf(float z){ return 1.f/(1.f+expf(-z)); }
__device__ __forceinline__ ushort f2bf(float f){
  uint32_t u=__float_as_uint(f);
  uint32_t r=(u + 0x7fffu + ((u>>16)&1u))>>16;
  return (ushort)r;
}
__device__ __forceinline__ float bf2f(ushort u){ return __uint_as_float(((uint32_t)u)<<16); }

__device__ __forceinline__ void async16(void* lds, const void* g){
  __builtin_amdgcn_global_load_lds(
      (const __attribute__((address_space(1))) uint32_t*)g,
      (__attribute__((address_space(3))) uint32_t*)lds,
      16, 0, 0);
}

// ---------- lj / li ----------
__global__ __launch_bounds__(256) void k_prep(const float* __restrict__ x,
    const float* __restrict__ Watt, float* __restrict__ lj, float* __restrict__ li)
{
  int bn = blockIdx.x*256 + threadIdx.x;
  const float4* xr = (const float4*)(x + (size_t)bn*CIN_);
  const float4* wq = (const float4*)(Watt);
  const float4* wk = (const float4*)(Watt + CIN_);
  float aq=0.f, ak=0.f;
  #pragma unroll 8
  for(int c=0;c<CIN_/4;++c){
    float4 xv=xr[c]; float4 q=wq[c]; float4 w=wk[c];
    aq += xv.x*q.x+xv.y*q.y+xv.z*q.z+xv.w*q.w;
    ak += xv.x*w.x+xv.y*w.y+xv.z*w.z+xv.w*w.w;
  }
  lj[bn]=aq; li[bn]=ak;
}

// ---------- casts ----------
__global__ __launch_bounds__(256) void k_cast(const float* __restrict__ s, ushort* __restrict__ d){
  int i = blockIdx.x*256 + threadIdx.x;
  float4 v = ((const float4*)s)[i];
  ((ushort4*)d)[i] = make_ushort4(f2bf(v.x), f2bf(v.y), f2bf(v.z), f2bf(v.w));
}
__global__ __launch_bounds__(256) void k_wgtb(const float* __restrict__ Wg, ushort* __restrict__ WgTb){
  int o=blockIdx.x, c=threadIdx.x;
  WgTb[(size_t)o*CIN_ + c] = f2bf(Wg[(size_t)c*OUT_ + o]);
}

// ---------- col union (exact top_k membership) + packed mask sum ----------
__global__ __launch_bounds__(256) void k_col(
    const float* __restrict__ m1, const float* __restrict__ m2,
    const float* __restrict__ sc, const float* __restrict__ lj,
    const float* __restrict__ li, const float* __restrict__ batt,
    float* __restrict__ colf, ushort* __restrict__ mrs)
{
  int row = blockIdx.x; int b = row >> 10; int t = threadIdx.x;
  size_t base = (size_t)row*N_ + 4*t;
  float4 m1v = *(const float4*)(m1 + base);
  float4 m2v = *(const float4*)(m2 + base);
  float4 scv = *(const float4*)(sc + (b<<10) + 4*t);
  float mr1[4] = {m1v.x*scv.x, m1v.y*scv.y, m1v.z*scv.z, m1v.w*scv.w};
  float mr2[4] = {m2v.x*scv.x, m2v.y*scv.y, m2v.z*scv.z, m2v.w*scv.w};
  *(ushort4*)(mrs + base) = make_ushort4(f2bf(mr1[0]+mr2[0]), f2bf(mr1[1]+mr2[1]),
                                         f2bf(mr1[2]+mr2[2]), f2bf(mr1[3]+mr2[3]));
  int z1=0,z2=0;
  #pragma unroll
  for(int k=0;k<4;++k){ z1 += (mr1[k]==0.f); z2 += (mr2[k]==0.f); }
  __shared__ int sc1[256], sc2[256];
  __shared__ float A1s[1024], A2s[1024];
  sc1[t]=z1; sc2[t]=z2; __syncthreads();
  for(int off=1; off<256; off<<=1){
    int a=0,c=0;
    if(t>=off){ a=sc1[t-off]; c=sc2[t-off]; }
    __syncthreads();
    if(t>=off){ sc1[t]+=a; sc2[t]+=c; }
    __syncthreads();
  }
  int excl1 = sc1[t]-z1, excl2 = sc2[t]-z2;
  int Z1 = sc1[255], Z2 = sc2[255];
  int P1 = 1024-Z1, P2 = 1024-Z2;
  bool rare = (P1>128)||(P2>256)||(Z1<128)||(Z2<128);
  if(!rare){
    int zb1=excl1, zb2=excl2;
    #pragma unroll
    for(int k=0;k<4;++k){
      bool q = (mr1[k]!=0.f) || (zb1<128) || (mr2[k]!=0.f) || (zb2<128) || (P2+zb2<256);
      if(q) colf[4*t+k]=1.0f;
      zb1 += (mr1[k]==0.f); zb2 += (mr2[k]==0.f);
    }
  } else {
    float lir = li[row], ba = batt[0];
    float4 ljv = *(const float4*)(lj + (b<<10) + 4*t);
    float ljr[4]={ljv.x,ljv.y,ljv.z,ljv.w};
    #pragma unroll
    for(int k=0;k<4;++k){
      float v = sigf(ljr[k]+lir+ba);
      A1s[4*t+k]=mr1[k]*v; A2s[4*t+k]=mr2[k]*v;
    }
    __syncthreads();
    for(int k=0;k<4;++k){
      int j=4*t+k; float a1j=A1s[j], a2j=A2s[j];
      int r1=0,r1m=0,r2=0,r2m=0;
      for(int jp=0;jp<1024;++jp){
        float p1=A1s[jp], p2=A2s[jp];
        bool lo = jp<j;
        r1  += (p1>a1j)||((p1==a1j)&&lo);
        r1m += (p1<a1j)||((p1==a1j)&&lo);
        r2  += (p2>a2j)||((p2==a2j)&&lo);
        r2m += (p2<a2j)||((p2==a2j)&&lo);
      }
      if(r1<128||r1m<128||r2<256||r2m<128) colf[j]=1.0f;
    }
  }
}

// ---------- At matrix (bf16 out) ----------
__global__ __launch_bounds__(256) void k_at(const ushort* __restrict__ mrs,
    const float* __restrict__ sc, const float* __restrict__ lj,
    const float* __restrict__ li, const float* __restrict__ batt,
    const float* __restrict__ colf, ushort* __restrict__ Atb)
{
  int row=blockIdx.x, t=threadIdx.x; int b=row>>10, i=row&1023;
  size_t base=(size_t)row*N_ + 4*t;
  ushort4 mv=*(const ushort4*)(mrs+base);
  float4 ljv=*(const float4*)(lj + (b<<10) + 4*t);
  float4 cv =*(const float4*)(colf + 4*t);
  float lir=li[row], ba=batt[0];
  float fi = (sc[(b<<10)+i]==0.f)?1.f:0.f;
  float mra[4]={bf2f(mv.x),bf2f(mv.y),bf2f(mv.z),bf2f(mv.w)};
  float ljr[4]={ljv.x,ljv.y,ljv.z,ljv.w};
  float cr[4]={cv.x,cv.y,cv.z,cv.w};
  ushort o[4]; int j0=4*t;
  #pragma unroll
  for(int k=0;k<4;++k){
    float v=sigf(ljr[k]+lir+ba);
    float val=v*mra[k]*cr[k];
    if(j0+k==i) val+=fi;
    o[k]=f2bf(val*(1.f/512.f));
  }
  *(ushort4*)(Atb+base) = make_ushort4(o[0],o[1],o[2],o[3]);
}

// ---------- bf16 MFMA NT GEMM: C[i][m] = sum_k A[i][k]*B[m][k] ----------
// BM=BN=128, BK=32, 256 threads (4 waves, 2x2 of 64x64), mfma_f32_16x16x32_bf16
__global__ __launch_bounds__(256) void mgemm(
    const ushort* __restrict__ A, int lda, long long sAb, long long sAg,
    const ushort* __restrict__ Bp, int ldb, long long sBb, long long sBg,
    float* __restrict__ C, ushort* __restrict__ Cb, int ldc, long long sCb, long long sCg,
    int K, int nG,
    const float* __restrict__ biasM, int biasMG,
    const float* __restrict__ biasN, int relu)
{
  __shared__ __align__(16) ushort As[128*32];
  __shared__ __align__(16) ushort Bs[128*32];
  int z=blockIdx.z, b=z/nG, g=z%nG;
  A  += b*sAb + g*sAg;
  Bp += b*sBb + g*sBg;
  size_t cOff = (size_t)b*sCb + (size_t)g*sCg;
  int m0 = blockIdx.y*128, n0 = blockIdx.x*128;
  int tid=threadIdx.x, w=tid>>6, lane=tid&63;
  int la=lane&15, hi=lane>>4;
  int wr=w>>1, wc=w&1;
  f32x4 acc[4][4] = {};
  int sr = tid>>2;          // staging row 0..63
  int sk = (tid&3)*8;       // k offset (elems)
  char* lA = (char*)As + w*1024;
  char* lB = (char*)Bs + w*1024;
  const ushort* gA0 = A + (size_t)(m0+sr)*lda + sk;
  const ushort* gA1 = A + (size_t)(m0+64+sr)*lda + sk;
  const ushort* gB0 = Bp + (size_t)(n0+sr)*ldb + sk;
  const ushort* gB1 = Bp + (size_t)(n0+64+sr)*ldb + sk;
  for(int k0=0;k0<K;k0+=32){
    async16(lA,        gA0 + k0);
    async16(lA + 4096, gA1 + k0);
    async16(lB,        gB0 + k0);
    async16(lB + 4096, gB1 + k0);
    __syncthreads();
    short8v af[4], bf[4];
    #pragma unroll
    for(int i2=0;i2<4;++i2) af[i2] = *(const short8v*)&As[(wr*64+i2*16+la)*32 + hi*8];
    #pragma unroll
    for(int j2=0;j2<4;++j2) bf[j2] = *(const short8v*)&Bs[(wc*64+j2*16+la)*32 + hi*8];
    #pragma unroll
    for(int i2=0;i2<4;++i2)
      #pragma unroll
      for(int j2=0;j2<4;++j2)
        acc[i2][j2] = __builtin_amdgcn_mfma_f32_16x16x32_bf16(af[i2], bf[j2], acc[i2][j2], 0,0,0);
    __syncthreads();
  }
  float* Cp = C + cOff;
  ushort* Cbp = Cb ? Cb + cOff : (ushort*)0;
  #pragma unroll
  for(int i2=0;i2<4;++i2){
    int row0 = m0 + wr*64 + i2*16 + hi*4;
    #pragma unroll
    for(int j2=0;j2<4;++j2){
      int col = n0 + wc*64 + j2*16 + la;
      float bn = biasN ? biasN[col] : 0.f;
      #pragma unroll
      for(int r=0;r<4;++r){
        int row = row0 + r;
        float v = acc[i2][j2][r] + bn + (biasM ? biasM[(size_t)g*biasMG + row] : 0.f);
        if(relu) v = fmaxf(v, 0.f);
        Cp[(size_t)row*ldc + col] = v;
        if(Cbp) Cbp[(size_t)row*ldc + col] = f2bf(v);
      }
    }
  }
}

// ---------- f32 NT GEMM (gconv2 only) ----------
template<int BM,int BN,int TM,int TN>
__global__ __launch_bounds__(256) void gemm_nt(
    const float* __restrict__ A, int lda, long long sAb, long long sAg,
    const float* __restrict__ Bp, int ldb, long long sBb, long long sBg,
    float* __restrict__ C, ushort* __restrict__ Cbd, int ldc, long long sCb, long long sCg,
    int K, int nG,
    const float* __restrict__ biasM, int biasMG,
    const float* __restrict__ biasN, int relu)
{
  static_assert(TN==4 && BM/TM==16 && BN/TN==16, "layout");
  constexpr int BK=32, LDSS=BK+4;
  int z=blockIdx.z, b=z/nG, g=z%nG;
  A  += b*sAb + g*sAg;
  Bp += b*sBb + g*sBg;
  size_t cOff = (size_t)b*sCb + (size_t)g*sCg;
  __shared__ float As[BM*LDSS];
  __shared__ float Bs[BN*LDSS];
  int tid=threadIdx.x;
  int tx=tid&15, ty=tid>>4;
  int m0=blockIdx.y*BM, n0=blockIdx.x*BN;
  float acc[TM][TN]={};
  for(int k0=0;k0<K;k0+=BK){
    #pragma unroll
    for(int u=0;u<BM*BK/1024;++u){
      int f=u*256+tid, r=f>>3, c=(f&7)*4;
      *(float4*)&As[r*LDSS+c] = *(const float4*)(A + (size_t)(m0+r)*lda + k0 + c);
    }
    #pragma unroll
    for(int u=0;u<BN*BK/1024;++u){
      int f=u*256+tid, r=f>>3, c=(f&7)*4;
      *(float4*)&Bs[r*LDSS+c] = *(const float4*)(Bp + (size_t)(n0+r)*ldb + k0 + c);
    }
    __syncthreads();
    #pragma unroll
    for(int kk=0;kk<BK;kk+=4){
      float4 av[TM]; float4 bv[TN];
      #pragma unroll
      for(int r=0;r<TM;++r) av[r]=*(const float4*)&As[(ty*TM+r)*LDSS+kk];
      #pragma unroll
      for(int c=0;c<TN;++c) bv[c]=*(const float4*)&Bs[(tx*TN+c)*LDSS+kk];
      #pragma unroll
      for(int r=0;r<TM;++r){
        #pragma unroll
        for(int c=0;c<TN;++c){
          acc[r][c] += av[r].x*bv[c].x + av[r].y*bv[c].y + av[r].z*bv[c].z + av[r].w*bv[c].w;
        }
      }
    }
    __syncthreads();
  }
  float4 bnv=make_float4(0.f,0.f,0.f,0.f);
  if(biasN){ bnv=*(const float4*)(biasN + n0 + tx*TN); }
  #pragma unroll
  for(int r=0;r<TM;++r){
    int m=m0+ty*TM+r;
    float bm = biasM ? biasM[(size_t)g*biasMG + m] : 0.f;
    float4 v;
    v.x=acc[r][0]+bm+bnv.x;
    v.y=acc[r][1]+bm+bnv.y;
    v.z=acc[r][2]+bm+bnv.z;
    v.w=acc[r][3]+bm+bnv.w;
    if(relu){ v.x=fmaxf(v.x,0.f); v.y=fmaxf(v.y,0.f); v.z=fmaxf(v.z,0.f); v.w=fmaxf(v.w,0.f); }
    *(float4*)(C + cOff + (size_t)m*ldc + n0 + tx*TN) = v;
    if(Cbd){
      *(ushort4*)(Cbd + cOff + (size_t)m*ldc + n0 + tx*TN) =
          make_ushort4(f2bf(v.x), f2bf(v.y), f2bf(v.z), f2bf(v.w));
    }
  }
}

// ---------- LN1 + residual ----------
__global__ __launch_bounds__(256) void k_ln1(const float* o1mT, const float* o1,
    const float* __restrict__ g1v, const float* __restrict__ be1, float* o1pT)
{
  int row=blockIdx.x, t=threadIdx.x; int b=row>>10, i=row&1023;
  float2 v = ((const float2*)(o1mT + (size_t)row*MID_))[t];
  float s=v.x+v.y, s2=v.x*v.x+v.y*v.y;
  for(int off=32; off; off>>=1){ s+=__shfl_down(s,off); s2+=__shfl_down(s2,off); }
  __shared__ float sm[8];
  int lane=t&63, wid=t>>6;
  if(lane==0){ sm[wid]=s; sm[4+wid]=s2; }
  __syncthreads();
  s=sm[0]+sm[1]+sm[2]+sm[3]; s2=sm[4]+sm[5]+sm[6]+sm[7];
  float mean=s*(1.f/MID_), var=s2*(1.f/MID_)-mean*mean;
  float rstd=rsqrtf(var+1e-6f);
  int m0=2*t;
  float a0=(v.x-mean)*rstd*g1v[m0]+be1[m0];
  float a1=(v.y-mean)*rstd*g1v[m0+1]+be1[m0+1];
  float2 o;
  o.x = a0 + o1[((size_t)(b*MID_+m0  ))*N_ + i];
  o.y = a1 + o1[((size_t)(b*MID_+m0+1))*N_ + i];
  ((float2*)(o1pT + (size_t)row*MID_))[t] = o;
}

// ---------- LN2 + final outputs ----------
__global__ __launch_bounds__(256) void k_ln2f(const float* o2mT, const float* o2,
    const float* __restrict__ g2v, const float* __restrict__ be2,
    float* node, float* out2)
{
  int row=blockIdx.x, t=threadIdx.x; int b=row>>10, i=row&1023;
  float v = o2mT[(size_t)row*OUT_ + t];
  float s=v, s2=v*v;
  for(int off=32; off; off>>=1){ s+=__shfl_down(s,off); s2+=__shfl_down(s2,off); }
  __shared__ float sm[8];
  int lane=t&63, wid=t>>6;
  if(lane==0){ sm[wid]=s; sm[4+wid]=s2; }
  __syncthreads();
  s=sm[0]+sm[1]+sm[2]+sm[3]; s2=sm[4]+sm[5]+sm[6]+sm[7];
  float mean=s*(1.f/OUT_); float var=s2*(1.f/OUT_)-mean*mean;
  float rstd=rsqrtf(var+1e-6f);
  float nf=(v-mean)*rstd*g2v[t]+be2[t];
  size_t ro=(size_t)row*OUT_+t;
  node[ro]=nf;
  out2[ro]=nf + o2[((size_t)(b*OUT_+t))*N_ + i];
}

extern "C" void kernel_launch(void* const* d_in, const int* in_sizes, int n_in,
                              void* d_out, int out_size, void* d_ws, size_t ws_size,
                              hipStream_t stream)
{
  const float* x    = (const float*)d_in[0];
  const float* m1   = (const float*)d_in[1];
  const float* m2   = (const float*)d_in[2];
  const float* sc   = (const float*)d_in[3];
  const float* gt   = (const float*)d_in[4];
  const float* Watt = (const float*)d_in[5];
  const float* batt = (const float*)d_in[6];
  const float* W1   = (const float*)d_in[7];
  const float* b1   = (const float*)d_in[8];
  const float* W2   = (const float*)d_in[9];
  const float* b2   = (const float*)d_in[10];
  const float* g1   = (const float*)d_in[11];
  const float* be1  = (const float*)d_in[12];
  const float* g2   = (const float*)d_in[13];
  const float* be2  = (const float*)d_in[14];
  const float* Wg   = (const float*)d_in[15];
  const float* bg   = (const float*)d_in[16];

  float* out2 = (float*)d_out;
  float* gtso = out2 + (size_t)B_*N_*OUT_;
  float* node = gtso + (size_t)B_*N_*OUT_;

  char* ws = (char*)d_ws;
  float*  colf = (float*)(ws);                       // 4 KB
  float*  lj   = (float*)(ws + 4096);                // 64 KB
  float*  li   = (float*)(ws + 69632);               // 64 KB
  ushort* WgTb = (ushort*)(ws + 135168);             // 128 KB
  ushort* W1b  = (ushort*)(ws + 266240);             // 64 KB
  ushort* gtb  = (ushort*)(ws + 331776);             // 8 MB
  ushort* Atb  = (ushort*)(ws + 8720384);            // 32 MB
  float*  o1   = (float*)(ws + 42274816);            // 32 MB f32
  ushort* o1b  = (ushort*)(ws + 75829248);           // 16 MB bf16
  char*   big32 = ws + 92606464;                     // 32 MB multi-use
  ushort* mrs  = (ushort*)big32;                     // k_col -> k_at
  ushort* xb   = (ushort*)big32;                     // cast_x -> gconv1
  float*  o1mT = (float*)big32;                      // GEMM1 -> ln1 (in-place) -> gconv2
  float*  o1pT = o1mT;
  float*  o2   = o1;                                 // o1 dead after ln1
  ushort* o2b  = o1b;                                // o1b dead after GEMM1
  float*  o2mT = o1mT;                               // o1pT dead after gconv2

  hipMemsetAsync(colf, 0, 4096, stream);
  k_prep<<<dim3(B_*N_/256),dim3(256),0,stream>>>(x,Watt,lj,li);
  k_col <<<dim3(B_*N_),dim3(256),0,stream>>>(m1,m2,sc,lj,li,batt,colf,mrs);
  k_at  <<<dim3(B_*N_),dim3(256),0,stream>>>(mrs,sc,lj,li,batt,colf,Atb);

  // casts (after k_at frees mrs/big32 for xb)
  k_cast<<<dim3(4096),dim3(256),0,stream>>>(x, xb);
  k_cast<<<dim3(4096),dim3(256),0,stream>>>(gt, gtb);
  k_cast<<<dim3(32),dim3(256),0,stream>>>(W1, W1b);
  k_wgtb<<<dim3(OUT_),dim3(256),0,stream>>>(Wg, WgTb);

  // gts = relu(gt @ Wg + bg): M=16384, N=256, K=256
  mgemm<<<dim3(2,128,1),256,0,stream>>>(
      gtb, CIN_, 0,0,
      WgTb, CIN_, 0,0,
      gtso, (ushort*)0, OUT_, 0,0,
      CIN_, 1, nullptr,0, bg, 1);

  // gconv1: per (b,g): o1[b,128g+m,n] = relu(W1g . x), dual f32+bf16 out
  mgemm<<<dim3(8,1,B_*4),256,0,stream>>>(
      W1b, 64, 0, (long long)128*64,
      xb, CIN_, (long long)N_*CIN_, 64,
      o1, o1b, N_, (long long)MID_*N_, (long long)128*N_,
      64, 4, b1, 128, nullptr, 1);

  // GEMM1: o1mT[b,i,m] = sum_j At[b,i,j]*o1[b,m,j]  (writes over xb)
  mgemm<<<dim3(4,8,B_),256,0,stream>>>(
      Atb, N_, (long long)N_*N_, 0,
      o1b, N_, (long long)MID_*N_, 0,
      o1mT, (ushort*)0, MID_, (long long)N_*MID_, 0,
      N_, 1, nullptr,0, nullptr, 0);

  k_ln1<<<dim3(B_*N_),256,0,stream>>>(o1mT, o1, g1, be1, o1pT);

  // gconv2 (f32): per (b,g): o2[b,64g+m,n] = relu(W2g . o1p), dual out
  gemm_nt<64,64,4,4><<<dim3(N_/64, 1, B_*4),256,0,stream>>>(
      W2, 128, 0, (long long)64*128,
      o1pT, MID_, (long long)N_*MID_, 128,
      o2, o2b, N_, (long long)OUT_*N_, (long long)64*N_,
      128, 4, b2, 64, nullptr, 1);

  // GEMM2: o2mT[b,i,m] = sum_j At[b,i,j]*o2[b,m,j]
  mgemm<<<dim3(2,8,B_),256,0,stream>>>(
      Atb, N_, (long long)N_*N_, 0,
      o2b, N_, (long long)OUT_*N_, 0,
      o2mT, (ushort*)0, OUT_, (long long)N_*OUT_, 0,
      N_, 1, nullptr,0, nullptr, 0);

  k_ln2f<<<dim3(B_*N_),256,0,stream>>>(o2mT, o2, g2, be2, node, out2);
}

// Round 3
// 465.199 us; speedup vs baseline: 2.4658x; 1.0068x over previous
//
#include <hip/hip_runtime.h>
#include <cstddef>
#include <cstdint>

#define B_ 16
#define N_ 1024
#define CIN_ 256
#define MID_ 512
#define OUT_ 256

typedef __attribute__((ext_vector_type(8))) short short8v;
typedef __attribute__((ext_vector_type(4))) float f32x4;

__device__ __forceinline__ float sigf(float z){ return 1.f/(1.f+expf(-z)); }
__device__ __forceinline__ ushort f2bf(float f){
  uint32_t u=__float_as_uint(f);
  uint32_t r=(u + 0x7fffu + ((u>>16)&1u))>>16;
  return (ushort)r;
}
__device__ __forceinline__ float bf2f(ushort u){ return __uint_as_float(((uint32_t)u)<<16); }

__device__ __forceinline__ void async16(void* lds, const void* g){
  __builtin_amdgcn_global_load_lds(
      (const __attribute__((address_space(1))) uint32_t*)g,
      (__attribute__((address_space(3))) uint32_t*)lds,
      16, 0, 0);
}

// ---------- lj / li ----------
__global__ __launch_bounds__(256) void k_prep(const float* __restrict__ x,
    const float* __restrict__ Watt, float* __restrict__ lj, float* __restrict__ li)
{
  int bn = blockIdx.x*256 + threadIdx.x;
  const float4* xr = (const float4*)(x + (size_t)bn*CIN_);
  const float4* wq = (const float4*)(Watt);
  const float4* wk = (const float4*)(Watt + CIN_);
  float aq=0.f, ak=0.f;
  #pragma unroll 8
  for(int c=0;c<CIN_/4;++c){
    float4 xv=xr[c]; float4 q=wq[c]; float4 w=wk[c];
    aq += xv.x*q.x+xv.y*q.y+xv.z*q.z+xv.w*q.w;
    ak += xv.x*w.x+xv.y*w.y+xv.z*w.z+xv.w*w.w;
  }
  lj[bn]=aq; li[bn]=ak;
}

// ---------- fused casts: x and gt (1M float4 each) ----------
__global__ __launch_bounds__(256) void k_cast2(const float* __restrict__ x,
    const float* __restrict__ gt, ushort* __restrict__ xb, ushort* __restrict__ gtb)
{
  int i = blockIdx.x*256 + threadIdx.x;
  int which = i>>20; int idx = i & 1048575;
  float4 v = ((const float4*)(which ? gt : x))[idx];
  ((ushort4*)(which ? gtb : xb))[idx] = make_ushort4(f2bf(v.x), f2bf(v.y), f2bf(v.z), f2bf(v.w));
}

// ---------- fused weight prep: W1b, W2b, WgTb ----------
__global__ __launch_bounds__(256) void k_wcast(const float* __restrict__ W1,
    const float* __restrict__ W2, const float* __restrict__ Wg,
    ushort* __restrict__ W1b, ushort* __restrict__ W2b, ushort* __restrict__ WgTb)
{
  int bid=blockIdx.x, t=threadIdx.x;
  if(bid<128){ int i=bid*256+t; W1b[i]=f2bf(W1[i]); }
  else if(bid<256){ int i=(bid-128)*256+t; W2b[i]=f2bf(W2[i]); }
  else { int idx=(bid-256)*256+t; int o=idx>>8, c=idx&255; WgTb[idx]=f2bf(Wg[(size_t)c*OUT_+o]); }
}

// ---------- col union: one wave per row, barrier-free ----------
__global__ __launch_bounds__(256) void k_col(
    const float* __restrict__ m1, const float* __restrict__ m2,
    const float* __restrict__ sc, const float* __restrict__ lj,
    const float* __restrict__ li, const float* __restrict__ batt,
    float* __restrict__ colf, ushort* __restrict__ mrs)
{
  int wid = threadIdx.x>>6, lane = threadIdx.x&63;
  int row = blockIdx.x*4 + wid; int b = row>>10;
  size_t base = (size_t)row*N_ + lane*16;
  const float4* m1p = (const float4*)(m1+base);
  const float4* m2p = (const float4*)(m2+base);
  const float4* scp = (const float4*)(sc + (b<<10) + lane*16);
  float mr1[16], mr2[16];
  int z1=0, z2=0;
  #pragma unroll
  for(int q=0;q<4;++q){
    float4 a=m1p[q], c=m2p[q], s=scp[q];
    mr1[4*q+0]=a.x*s.x; mr1[4*q+1]=a.y*s.y; mr1[4*q+2]=a.z*s.z; mr1[4*q+3]=a.w*s.w;
    mr2[4*q+0]=c.x*s.x; mr2[4*q+1]=c.y*s.y; mr2[4*q+2]=c.z*s.z; mr2[4*q+3]=c.w*s.w;
    #pragma unroll
    for(int k=0;k<4;++k){ z1 += (mr1[4*q+k]==0.f); z2 += (mr2[4*q+k]==0.f); }
  }
  // write mrs = bf16(mr1+mr2)
  ushort mb[16];
  #pragma unroll
  for(int k=0;k<16;++k) mb[k]=f2bf(mr1[k]+mr2[k]);
  *(short8v*)(mrs+base)   = *(short8v*)&mb[0];
  *(short8v*)(mrs+base+8) = *(short8v*)&mb[8];
  // wave inclusive scans of zero counts
  int s1=z1, s2=z2;
  #pragma unroll
  for(int off=1; off<64; off<<=1){
    int t1=__shfl_up(s1,off), t2=__shfl_up(s2,off);
    if(lane>=off){ s1+=t1; s2+=t2; }
  }
  int excl1=s1-z1, excl2=s2-z2;
  int Z1=__shfl(s1,63), Z2=__shfl(s2,63);
  int P1=1024-Z1, P2=1024-Z2;
  bool rare = (P1>128)||(P2>256)||(Z1<128)||(Z2<128);
  if(!rare){
    int zb1=excl1, zb2=excl2;
    #pragma unroll
    for(int k=0;k<16;++k){
      bool q = (mr1[k]!=0.f) || (zb1<128) || (mr2[k]!=0.f) || (zb2<128) || (P2+zb2<256);
      if(q) colf[lane*16+k]=1.0f;
      zb1 += (mr1[k]==0.f); zb2 += (mr2[k]==0.f);
    }
  } else {
    // exact rank fallback (statistically never taken on this distribution)
    float lir=li[row], ba=batt[0];
    const float* m1r = m1 + (size_t)row*N_;
    const float* m2r = m2 + (size_t)row*N_;
    const float* scr = sc + (b<<10);
    const float* ljr = lj + (b<<10);
    float a1v[16], a2v[16];
    #pragma unroll
    for(int k=0;k<16;++k){
      float v = sigf(ljr[lane*16+k]+lir+ba);
      a1v[k]=mr1[k]*v; a2v[k]=mr2[k]*v;
    }
    for(int k=0;k<16;++k){
      int j = lane*16+k;
      int c1=0,c1m=0,c2=0,c2m=0;
      for(int jp=0;jp<N_;++jp){
        float sv=scr[jp];
        float vv=sigf(ljr[jp]+lir+ba);
        float p1=m1r[jp]*sv*vv, p2=m2r[jp]*sv*vv;
        bool lo = jp<j;
        c1 += (p1>a1v[k])||((p1==a1v[k])&&lo);
        c1m+= (p1<a1v[k])||((p1==a1v[k])&&lo);
        c2 += (p2>a2v[k])||((p2==a2v[k])&&lo);
        c2m+= (p2<a2v[k])||((p2==a2v[k])&&lo);
      }
      if(c1<128||c1m<128||c2<256||c2m<128) colf[j]=1.0f;
    }
  }
}

// ---------- At matrix (bf16 out) ----------
__global__ __launch_bounds__(256) void k_at(const ushort* __restrict__ mrs,
    const float* __restrict__ sc, const float* __restrict__ lj,
    const float* __restrict__ li, const float* __restrict__ batt,
    const float* __restrict__ colf, ushort* __restrict__ Atb)
{
  int row=blockIdx.x, t=threadIdx.x; int b=row>>10, i=row&1023;
  size_t base=(size_t)row*N_ + 4*t;
  ushort4 mv=*(const ushort4*)(mrs+base);
  float4 ljv=*(const float4*)(lj + (b<<10) + 4*t);
  float4 cv =*(const float4*)(colf + 4*t);
  float lir=li[row], ba=batt[0];
  float fi = (sc[(b<<10)+i]==0.f)?1.f:0.f;
  float mra[4]={bf2f(mv.x),bf2f(mv.y),bf2f(mv.z),bf2f(mv.w)};
  float ljr[4]={ljv.x,ljv.y,ljv.z,ljv.w};
  float cr[4]={cv.x,cv.y,cv.z,cv.w};
  ushort o[4]; int j0=4*t;
  #pragma unroll
  for(int k=0;k<4;++k){
    float v=sigf(ljr[k]+lir+ba);
    float val=v*mra[k]*cr[k];
    if(j0+k==i) val+=fi;
    o[k]=f2bf(val*(1.f/512.f));
  }
  *(ushort4*)(Atb+base) = make_ushort4(o[0],o[1],o[2],o[3]);
}

// ---------- bf16 MFMA NT GEMM (templated tile): C[i][m]=sum_k A[i][k]*B[m][k] ----------
template<int BM,int BN,int WR,int WC>
__global__ __launch_bounds__(256) void mgemm(
    const ushort* __restrict__ A, int lda, long long sAb, long long sAg,
    const ushort* __restrict__ Bp, int ldb, long long sBb, long long sBg,
    float* __restrict__ C, ushort* __restrict__ Cb, int ldc, long long sCb, long long sCg,
    int K, int nG,
    const float* __restrict__ biasM, int biasMG,
    const float* __restrict__ biasN, int relu)
{
  static_assert(WR*WC==4 && BM==WR*64 && BN==WC*64, "tile");
  __shared__ __align__(16) ushort As[BM*32];
  __shared__ __align__(16) ushort Bs[BN*32];
  int z=blockIdx.z, b=z/nG, g=z%nG;
  A  += (size_t)b*sAb + (size_t)g*sAg;
  Bp += (size_t)b*sBb + (size_t)g*sBg;
  size_t cOff = (size_t)b*sCb + (size_t)g*sCg;
  int m0 = blockIdx.y*BM, n0 = blockIdx.x*BN;
  int tid=threadIdx.x, w=tid>>6, lane=tid&63;
  int la=lane&15, hi=lane>>4;
  int wr=w/WC, wc=w%WC;
  f32x4 acc[4][4] = {};
  constexpr int RND = (BM+BN)/64;
  int srow = lane>>2;        // 0..15 within wave's 16 staged rows
  int sk8  = (lane&3)*8;     // elem offset within row
  for(int k0=0;k0<K;k0+=32){
    #pragma unroll
    for(int r=0;r<RND;++r){
      int row0 = r*64 + w*16;              // wave-uniform
      if(row0 < BM){
        const ushort* src = A + (size_t)(m0+row0+srow)*lda + k0 + sk8;
        async16((char*)As + row0*64, src);
      } else {
        const ushort* src = Bp + (size_t)(n0+row0-BM+srow)*ldb + k0 + sk8;
        async16((char*)Bs + (row0-BM)*64, src);
      }
    }
    __syncthreads();
    short8v af[4], bf4[4];
    #pragma unroll
    for(int i2=0;i2<4;++i2) af[i2] = *(const short8v*)&As[(wr*64+i2*16+la)*32 + hi*8];
    #pragma unroll
    for(int j2=0;j2<4;++j2) bf4[j2] = *(const short8v*)&Bs[(wc*64+j2*16+la)*32 + hi*8];
    #pragma unroll
    for(int i2=0;i2<4;++i2)
      #pragma unroll
      for(int j2=0;j2<4;++j2)
        acc[i2][j2] = __builtin_amdgcn_mfma_f32_16x16x32_bf16(af[i2], bf4[j2], acc[i2][j2], 0,0,0);
    __syncthreads();
  }
  #pragma unroll
  for(int i2=0;i2<4;++i2){
    int row0 = m0 + wr*64 + i2*16 + hi*4;
    #pragma unroll
    for(int j2=0;j2<4;++j2){
      int col = n0 + wc*64 + j2*16 + la;
      float bn = biasN ? biasN[col] : 0.f;
      #pragma unroll
      for(int r=0;r<4;++r){
        int row = row0 + r;
        float v = acc[i2][j2][r] + bn + (biasM ? biasM[(size_t)g*biasMG + row] : 0.f);
        if(relu) v = fmaxf(v, 0.f);
        if(C)  C [cOff + (size_t)row*ldc + col] = v;
        if(Cb) Cb[cOff + (size_t)row*ldc + col] = f2bf(v);
      }
    }
  }
}

// ---------- LN1 + bf16 residual -> bf16 out ----------
__global__ __launch_bounds__(256) void k_ln1(const float* __restrict__ o1mT,
    const ushort* __restrict__ o1b,
    const float* __restrict__ g1v, const float* __restrict__ be1, ushort* __restrict__ o1pb)
{
  int row=blockIdx.x, t=threadIdx.x; int b=row>>10, i=row&1023;
  float2 v = ((const float2*)(o1mT + (size_t)row*MID_))[t];
  float s=v.x+v.y, s2=v.x*v.x+v.y*v.y;
  for(int off=32; off; off>>=1){ s+=__shfl_down(s,off); s2+=__shfl_down(s2,off); }
  __shared__ float sm[8];
  int lane=t&63, wid=t>>6;
  if(lane==0){ sm[wid]=s; sm[4+wid]=s2; }
  __syncthreads();
  s=sm[0]+sm[1]+sm[2]+sm[3]; s2=sm[4]+sm[5]+sm[6]+sm[7];
  float mean=s*(1.f/MID_), var=s2*(1.f/MID_)-mean*mean;
  float rstd=rsqrtf(var+1e-6f);
  int m0=2*t;
  float a0=(v.x-mean)*rstd*g1v[m0]+be1[m0];
  float a1=(v.y-mean)*rstd*g1v[m0+1]+be1[m0+1];
  float r0 = bf2f(o1b[((size_t)(b*MID_+m0  ))*N_ + i]);
  float r1 = bf2f(o1b[((size_t)(b*MID_+m0+1))*N_ + i]);
  ushort2 o; o.x=f2bf(a0+r0); o.y=f2bf(a1+r1);
  ((ushort2*)(o1pb + (size_t)row*MID_))[t] = o;
}

// ---------- LN2 + final outputs (bf16 residual) ----------
__global__ __launch_bounds__(256) void k_ln2f(const float* __restrict__ o2mT,
    const ushort* __restrict__ o2b,
    const float* __restrict__ g2v, const float* __restrict__ be2,
    float* __restrict__ node, float* __restrict__ out2)
{
  int row=blockIdx.x, t=threadIdx.x; int b=row>>10, i=row&1023;
  float v = o2mT[(size_t)row*OUT_ + t];
  float s=v, s2=v*v;
  for(int off=32; off; off>>=1){ s+=__shfl_down(s,off); s2+=__shfl_down(s2,off); }
  __shared__ float sm[8];
  int lane=t&63, wid=t>>6;
  if(lane==0){ sm[wid]=s; sm[4+wid]=s2; }
  __syncthreads();
  s=sm[0]+sm[1]+sm[2]+sm[3]; s2=sm[4]+sm[5]+sm[6]+sm[7];
  float mean=s*(1.f/OUT_); float var=s2*(1.f/OUT_)-mean*mean;
  float rstd=rsqrtf(var+1e-6f);
  float nf=(v-mean)*rstd*g2v[t]+be2[t];
  size_t ro=(size_t)row*OUT_+t;
  node[ro]=nf;
  out2[ro]=nf + bf2f(o2b[((size_t)(b*OUT_+t))*N_ + i]);
}

extern "C" void kernel_launch(void* const* d_in, const int* in_sizes, int n_in,
                              void* d_out, int out_size, void* d_ws, size_t ws_size,
                              hipStream_t stream)
{
  const float* x    = (const float*)d_in[0];
  const float* m1   = (const float*)d_in[1];
  const float* m2   = (const float*)d_in[2];
  const float* sc   = (const float*)d_in[3];
  const float* gt   = (const float*)d_in[4];
  const float* Watt = (const float*)d_in[5];
  const float* batt = (const float*)d_in[6];
  const float* W1   = (const float*)d_in[7];
  const float* b1   = (const float*)d_in[8];
  const float* W2   = (const float*)d_in[9];
  const float* b2   = (const float*)d_in[10];
  const float* g1   = (const float*)d_in[11];
  const float* be1  = (const float*)d_in[12];
  const float* g2   = (const float*)d_in[13];
  const float* be2  = (const float*)d_in[14];
  const float* Wg   = (const float*)d_in[15];
  const float* bg   = (const float*)d_in[16];

  float* out2 = (float*)d_out;
  float* gtso = out2 + (size_t)B_*N_*OUT_;
  float* node = gtso + (size_t)B_*N_*OUT_;

  char* ws = (char*)d_ws;
  float*  colf = (float*)(ws);                 // 4 KB
  float*  lj   = (float*)(ws + 4096);          // 64 KB
  float*  li   = (float*)(ws + 69632);         // 64 KB
  ushort* W1b  = (ushort*)(ws + 135168);       // 64 KB
  ushort* W2b  = (ushort*)(ws + 200704);       // 64 KB
  ushort* WgTb = (ushort*)(ws + 266240);       // 128 KB
  // R1 (32 MB): mrs -> o1mT
  char* R1 = ws + 1048576;
  ushort* mrs  = (ushort*)R1;
  float*  o1mT = (float*)R1;
  // R2 (32 MB): Atb
  ushort* Atb  = (ushort*)(ws + 34603008);
  // R3 (16 MB): xb(8) | gtb(8) -> o2b(8)
  char* R3 = ws + 68157440;
  ushort* xb  = (ushort*)R3;
  ushort* gtb = (ushort*)(R3 + 8388608);
  ushort* o2b = (ushort*)R3;
  // R4 (16 MB): o1b
  ushort* o1b = (ushort*)(ws + 84934656);
  // R5 (16 MB): o1pb -> o2mT
  char* R5 = ws + 101711872;
  ushort* o1pb = (ushort*)R5;
  float*  o2mT = (float*)R5;

  hipMemsetAsync(colf, 0, 4096, stream);
  k_prep <<<dim3(B_*N_/256),dim3(256),0,stream>>>(x,Watt,lj,li);
  k_cast2<<<dim3(8192),dim3(256),0,stream>>>(x, gt, xb, gtb);
  k_wcast<<<dim3(512),dim3(256),0,stream>>>(W1, W2, Wg, W1b, W2b, WgTb);
  k_col  <<<dim3(B_*N_/4),dim3(256),0,stream>>>(m1,m2,sc,lj,li,batt,colf,mrs);
  k_at   <<<dim3(B_*N_),dim3(256),0,stream>>>(mrs,sc,lj,li,batt,colf,Atb);

  // gts = relu(gt @ Wg + bg): M=16384, N=256, K=256
  mgemm<128,128,2,2><<<dim3(2,128,1),256,0,stream>>>(
      gtb, CIN_, 0,0,
      WgTb, CIN_, 0,0,
      gtso, (ushort*)0, OUT_, 0,0,
      CIN_, 1, nullptr,0, bg, 1);

  // gconv1: per (b,g): o1b[b,128g+m,n] = relu(W1g . x)  (bf16 only)
  mgemm<128,128,2,2><<<dim3(8,1,B_*4),256,0,stream>>>(
      W1b, 64, 0, (long long)128*64,
      xb, CIN_, (long long)N_*CIN_, 64,
      (float*)0, o1b, N_, (long long)MID_*N_, (long long)128*N_,
      64, 4, b1, 128, nullptr, 1);

  // GEMM1: o1mT[b,i,m] = sum_j At[b,i,j]*o1[b,m,j]
  mgemm<128,128,2,2><<<dim3(4,8,B_),256,0,stream>>>(
      Atb, N_, (long long)N_*N_, 0,
      o1b, N_, (long long)MID_*N_, 0,
      o1mT, (ushort*)0, MID_, (long long)N_*MID_, 0,
      N_, 1, nullptr,0, nullptr, 0);

  k_ln1<<<dim3(B_*N_),256,0,stream>>>(o1mT, o1b, g1, be1, o1pb);

  // gconv2: per (b,g): o2b[b,64g+m,n] = relu(W2g . o1p)  (bf16 only)
  mgemm<64,256,1,4><<<dim3(4,1,B_*4),256,0,stream>>>(
      W2b, 128, 0, (long long)64*128,
      o1pb, MID_, (long long)N_*MID_, 128,
      (float*)0, o2b, N_, (long long)OUT_*N_, (long long)64*N_,
      128, 4, b2, 64, nullptr, 1);

  // GEMM2: o2mT[b,i,m] = sum_j At[b,i,j]*o2[b,m,j]
  mgemm<128,128,2,2><<<dim3(2,8,B_),256,0,stream>>>(
      Atb, N_, (long long)N_*N_, 0,
      o2b, N_, (long long)OUT_*N_, 0,
      o2mT, (ushort*)0, OUT_, (long long)N_*OUT_, 0,
      N_, 1, nullptr,0, nullptr, 0);

  k_ln2f<<<dim3(B_*N_),256,0,stream>>>(o2mT, o2b, g2, be2, node, out2);
}

// Round 4
// 398.356 us; speedup vs baseline: 2.8795x; 1.1678x over previous
//
#include <hip/hip_runtime.h>
#include <cstddef>
#include <cstdint>

#define B_ 16
#define N_ 1024
#define CIN_ 256
#define MID_ 512
#define OUT_ 256

typedef __attribute__((ext_vector_type(8))) short short8v;
typedef __attribute__((ext_vector_type(4))) float f32x4;

__device__ __forceinline__ float sigf(float z){ return 1.f/(1.f+expf(-z)); }
__device__ __forceinline__ ushort f2bf(float f){
  uint32_t u=__float_as_uint(f);
  uint32_t r=(u + 0x7fffu + ((u>>16)&1u))>>16;
  return (ushort)r;
}
__device__ __forceinline__ float bf2f(ushort u){ return __uint_as_float(((uint32_t)u)<<16); }

__device__ __forceinline__ void async16(void* lds, const void* g){
  __builtin_amdgcn_global_load_lds(
      (const __attribute__((address_space(1))) uint32_t*)g,
      (__attribute__((address_space(3))) uint32_t*)lds,
      16, 0, 0);
}

// ---------- fused: lj/li dot products + bf16 casts of x and gt ----------
__global__ __launch_bounds__(256) void k_pc(const float* __restrict__ x,
    const float* __restrict__ gt, const float* __restrict__ Watt,
    float* __restrict__ lj, float* __restrict__ li,
    ushort* __restrict__ xb, ushort* __restrict__ gtb)
{
  int bid=blockIdx.x, wid=threadIdx.x>>6, lane=threadIdx.x&63;
  if(bid < 4096){
    int row = bid*4 + wid;
    float4 xv = ((const float4*)(x + (size_t)row*CIN_))[lane];
    ((ushort4*)(xb + (size_t)row*CIN_))[lane] =
        make_ushort4(f2bf(xv.x), f2bf(xv.y), f2bf(xv.z), f2bf(xv.w));
    float4 q = ((const float4*)Watt)[lane];
    float4 w = ((const float4*)(Watt + CIN_))[lane];
    float aq = xv.x*q.x+xv.y*q.y+xv.z*q.z+xv.w*q.w;
    float ak = xv.x*w.x+xv.y*w.y+xv.z*w.z+xv.w*w.w;
    #pragma unroll
    for(int off=32; off; off>>=1){ aq += __shfl_xor(aq,off); ak += __shfl_xor(ak,off); }
    if(lane==0){ lj[row]=aq; li[row]=ak; }
  } else {
    int row = (bid-4096)*4 + wid;
    float4 v = ((const float4*)(gt + (size_t)row*CIN_))[lane];
    ((ushort4*)(gtb + (size_t)row*CIN_))[lane] =
        make_ushort4(f2bf(v.x), f2bf(v.y), f2bf(v.z), f2bf(v.w));
  }
}

// ---------- fused weight prep: W1b, W2b, WgTb ----------
__global__ __launch_bounds__(256) void k_wcast(const float* __restrict__ W1,
    const float* __restrict__ W2, const float* __restrict__ Wg,
    ushort* __restrict__ W1b, ushort* __restrict__ W2b, ushort* __restrict__ WgTb)
{
  int bid=blockIdx.x, t=threadIdx.x;
  if(bid<128){ int i=bid*256+t; W1b[i]=f2bf(W1[i]); }
  else if(bid<256){ int i=(bid-128)*256+t; W2b[i]=f2bf(W2[i]); }
  else { int idx=(bid-256)*256+t; int o=idx>>8, c=idx&255; WgTb[idx]=f2bf(Wg[(size_t)c*OUT_+o]); }
}

// ---------- col union: block per row, wave-scan + 1 barrier ----------
__global__ __launch_bounds__(256) void k_col(
    const float* __restrict__ m1, const float* __restrict__ m2,
    const float* __restrict__ sc, const float* __restrict__ lj,
    const float* __restrict__ li, const float* __restrict__ batt,
    float* __restrict__ colf, ushort* __restrict__ mrs)
{
  int row = blockIdx.x; int b = row >> 10; int t = threadIdx.x;
  int lane = t&63, wid = t>>6;
  size_t base = (size_t)row*N_ + 4*t;
  float4 m1v = *(const float4*)(m1 + base);
  float4 m2v = *(const float4*)(m2 + base);
  float4 scv = *(const float4*)(sc + (b<<10) + 4*t);
  float mr1[4] = {m1v.x*scv.x, m1v.y*scv.y, m1v.z*scv.z, m1v.w*scv.w};
  float mr2[4] = {m2v.x*scv.x, m2v.y*scv.y, m2v.z*scv.z, m2v.w*scv.w};
  *(ushort4*)(mrs + base) = make_ushort4(f2bf(mr1[0]+mr2[0]), f2bf(mr1[1]+mr2[1]),
                                         f2bf(mr1[2]+mr2[2]), f2bf(mr1[3]+mr2[3]));
  int z1=0,z2=0;
  #pragma unroll
  for(int k=0;k<4;++k){ z1 += (mr1[k]==0.f); z2 += (mr2[k]==0.f); }
  // packed wave inclusive scan: z1 low 16, z2 high 16
  int s = z1 | (z2<<16);
  #pragma unroll
  for(int off=1; off<64; off<<=1){
    int u = __shfl_up(s,off);
    if(lane>=off) s += u;
  }
  __shared__ int wsum[4];
  if(lane==63) wsum[wid]=s;
  __syncthreads();
  int prev=0, tot=0;
  #pragma unroll
  for(int w2=0;w2<4;++w2){ int v=wsum[w2]; tot+=v; if(w2<wid) prev+=v; }
  int incl = s + prev;
  int z1i = incl & 0xffff, z2i = incl >> 16;
  int excl1 = z1i - z1, excl2 = z2i - z2;
  int Z1 = tot & 0xffff, Z2 = tot >> 16;
  int P1 = 1024-Z1, P2 = 1024-Z2;
  bool rare = (P1>128)||(P2>256)||(Z1<128)||(Z2<128);
  if(!rare){
    int zb1=excl1, zb2=excl2;
    #pragma unroll
    for(int k=0;k<4;++k){
      bool q = (mr1[k]!=0.f) || (zb1<128) || (mr2[k]!=0.f) || (zb2<128) || (P2+zb2<256);
      if(q) colf[4*t+k]=1.0f;
      zb1 += (mr1[k]==0.f); zb2 += (mr2[k]==0.f);
    }
  } else {
    // exact rank fallback (statistically never taken); recompute from global
    float lir=li[row], ba=batt[0];
    const float* m1r = m1 + (size_t)row*N_;
    const float* m2r = m2 + (size_t)row*N_;
    const float* scr = sc + (b<<10);
    const float* ljr = lj + (b<<10);
    float a1v[4], a2v[4];
    #pragma unroll
    for(int k=0;k<4;++k){
      float v = sigf(ljr[4*t+k]+lir+ba);
      a1v[k]=mr1[k]*v; a2v[k]=mr2[k]*v;
    }
    int c1[4]={0,0,0,0}, c1m[4]={0,0,0,0}, c2[4]={0,0,0,0}, c2m[4]={0,0,0,0};
    for(int jp=0;jp<N_;++jp){
      float vv = sigf(ljr[jp]+lir+ba);
      float p1 = m1r[jp]*scr[jp]*vv, p2 = m2r[jp]*scr[jp]*vv;
      #pragma unroll
      for(int k=0;k<4;++k){
        bool lo = jp < 4*t+k;
        c1[k] += (p1>a1v[k])||((p1==a1v[k])&&lo);
        c1m[k]+= (p1<a1v[k])||((p1==a1v[k])&&lo);
        c2[k] += (p2>a2v[k])||((p2==a2v[k])&&lo);
        c2m[k]+= (p2<a2v[k])||((p2==a2v[k])&&lo);
      }
    }
    #pragma unroll
    for(int k=0;k<4;++k)
      if(c1[k]<128||c1m[k]<128||c2[k]<256||c2m[k]<128) colf[4*t+k]=1.0f;
  }
}

// ---------- At matrix (bf16 out) ----------
__global__ __launch_bounds__(256) void k_at(const ushort* __restrict__ mrs,
    const float* __restrict__ sc, const float* __restrict__ lj,
    const float* __restrict__ li, const float* __restrict__ batt,
    const float* __restrict__ colf, ushort* __restrict__ Atb)
{
  int row=blockIdx.x, t=threadIdx.x; int b=row>>10, i=row&1023;
  size_t base=(size_t)row*N_ + 4*t;
  ushort4 mv=*(const ushort4*)(mrs+base);
  float4 ljv=*(const float4*)(lj + (b<<10) + 4*t);
  float4 cv =*(const float4*)(colf + 4*t);
  float lir=li[row], ba=batt[0];
  float fi = (sc[(b<<10)+i]==0.f)?1.f:0.f;
  float mra[4]={bf2f(mv.x),bf2f(mv.y),bf2f(mv.z),bf2f(mv.w)};
  float ljr[4]={ljv.x,ljv.y,ljv.z,ljv.w};
  float cr[4]={cv.x,cv.y,cv.z,cv.w};
  ushort o[4]; int j0=4*t;
  #pragma unroll
  for(int k=0;k<4;++k){
    float v=sigf(ljr[k]+lir+ba);
    float val=v*mra[k]*cr[k];
    if(j0+k==i) val+=fi;
    o[k]=f2bf(val*(1.f/512.f));
  }
  *(ushort4*)(Atb+base) = make_ushort4(o[0],o[1],o[2],o[3]);
}

// ---------- bf16 MFMA NT GEMM: C[i][m]=sum_k A[i][k]*B[m][k] ----------
// optional CbT: transposed bf16 copy CbT[col][row]
template<int BM,int BN,int WR,int WC,int BK>
__global__ __launch_bounds__(256) void mgemm(
    const ushort* __restrict__ A, int lda, long long sAb, long long sAg,
    const ushort* __restrict__ Bp, int ldb, long long sBb, long long sBg,
    float* __restrict__ C, ushort* __restrict__ Cb, int ldc, long long sCb, long long sCg,
    ushort* __restrict__ CbT, long long sTb, long long sTg, int ldt,
    int K, int nG,
    const float* __restrict__ biasM, int biasMG,
    const float* __restrict__ biasN, int relu)
{
  static_assert(WR*WC==4 && BM==WR*64 && BN==WC*64, "tile");
  static_assert((BM*BK)%512==0 && (BN*BK)%512==0, "stage align");
  __shared__ __align__(16) ushort As[BM*BK];
  __shared__ __align__(16) ushort Bs[BN*BK];
  int z=blockIdx.z, b=z/nG, g=z%nG;
  A  += (size_t)b*sAb + (size_t)g*sAg;
  Bp += (size_t)b*sBb + (size_t)g*sBg;
  size_t cOff = (size_t)b*sCb + (size_t)g*sCg;
  size_t tOff = (size_t)b*sTb + (size_t)g*sTg;
  int m0 = blockIdx.y*BM, n0 = blockIdx.x*BN;
  int tid=threadIdx.x, w=tid>>6, lane=tid&63;
  int la=lane&15, hi=lane>>4;
  int wr=w/WC, wc=w%WC;
  f32x4 acc[4][4] = {};
  constexpr int ISS = (BM+BN)*BK/2048;
  for(int k0=0;k0<K;k0+=BK){
    #pragma unroll
    for(int r=0;r<ISS;++r){
      int e = (r*256 + tid)*8;
      if(e < BM*BK){
        int row=e/BK, kk=e%BK;
        async16((char*)As + (size_t)e*2, A + (size_t)(m0+row)*lda + k0+kk);
      } else {
        int e2=e-BM*BK; int row=e2/BK, kk=e2%BK;
        async16((char*)Bs + (size_t)e2*2, Bp + (size_t)(n0+row)*ldb + k0+kk);
      }
    }
    __syncthreads();
    #pragma unroll
    for(int h=0;h<BK/32;++h){
      short8v af[4], bf4[4];
      #pragma unroll
      for(int i2=0;i2<4;++i2) af[i2] = *(const short8v*)&As[(wr*64+i2*16+la)*BK + h*32 + hi*8];
      #pragma unroll
      for(int j2=0;j2<4;++j2) bf4[j2] = *(const short8v*)&Bs[(wc*64+j2*16+la)*BK + h*32 + hi*8];
      #pragma unroll
      for(int i2=0;i2<4;++i2)
        #pragma unroll
        for(int j2=0;j2<4;++j2)
          acc[i2][j2] = __builtin_amdgcn_mfma_f32_16x16x32_bf16(af[i2], bf4[j2], acc[i2][j2], 0,0,0);
    }
    __syncthreads();
  }
  #pragma unroll
  for(int i2=0;i2<4;++i2){
    int row0 = m0 + wr*64 + i2*16 + hi*4;
    #pragma unroll
    for(int j2=0;j2<4;++j2){
      int col = n0 + wc*64 + j2*16 + la;
      float bn = biasN ? biasN[col] : 0.f;
      #pragma unroll
      for(int r=0;r<4;++r){
        int row = row0 + r;
        float v = acc[i2][j2][r] + bn + (biasM ? biasM[(size_t)g*biasMG + row] : 0.f);
        if(relu) v = fmaxf(v, 0.f);
        if(C)   C  [cOff + (size_t)row*ldc + col] = v;
        if(Cb)  Cb [cOff + (size_t)row*ldc + col] = f2bf(v);
        if(CbT) CbT[tOff + (size_t)col*ldt + row] = f2bf(v);
      }
    }
  }
}

// ---------- LN1 + bf16 residual (contig) -> bf16 out ----------
__global__ __launch_bounds__(256) void k_ln1(const float* __restrict__ o1mT,
    const ushort* __restrict__ o1bT,
    const float* __restrict__ g1v, const float* __restrict__ be1, ushort* __restrict__ o1pb)
{
  int row=blockIdx.x, t=threadIdx.x;
  float2 v = ((const float2*)(o1mT + (size_t)row*MID_))[t];
  float s=v.x+v.y, s2=v.x*v.x+v.y*v.y;
  for(int off=32; off; off>>=1){ s+=__shfl_down(s,off); s2+=__shfl_down(s2,off); }
  __shared__ float sm[8];
  int lane=t&63, wid=t>>6;
  if(lane==0){ sm[wid]=s; sm[4+wid]=s2; }
  __syncthreads();
  s=sm[0]+sm[1]+sm[2]+sm[3]; s2=sm[4]+sm[5]+sm[6]+sm[7];
  float mean=s*(1.f/MID_), var=s2*(1.f/MID_)-mean*mean;
  float rstd=rsqrtf(var+1e-6f);
  int m0=2*t;
  float a0=(v.x-mean)*rstd*g1v[m0]+be1[m0];
  float a1=(v.y-mean)*rstd*g1v[m0+1]+be1[m0+1];
  ushort2 rr = ((const ushort2*)(o1bT + (size_t)row*MID_))[t];
  ushort2 o; o.x=f2bf(a0+bf2f(rr.x)); o.y=f2bf(a1+bf2f(rr.y));
  ((ushort2*)(o1pb + (size_t)row*MID_))[t] = o;
}

// ---------- LN2 + final outputs (contig residual) ----------
__global__ __launch_bounds__(256) void k_ln2f(const float* __restrict__ o2mT,
    const ushort* __restrict__ o2bT,
    const float* __restrict__ g2v, const float* __restrict__ be2,
    float* __restrict__ node, float* __restrict__ out2)
{
  int row=blockIdx.x, t=threadIdx.x;
  float v = o2mT[(size_t)row*OUT_ + t];
  float s=v, s2=v*v;
  for(int off=32; off; off>>=1){ s+=__shfl_down(s,off); s2+=__shfl_down(s2,off); }
  __shared__ float sm[8];
  int lane=t&63, wid=t>>6;
  if(lane==0){ sm[wid]=s; sm[4+wid]=s2; }
  __syncthreads();
  s=sm[0]+sm[1]+sm[2]+sm[3]; s2=sm[4]+sm[5]+sm[6]+sm[7];
  float mean=s*(1.f/OUT_); float var=s2*(1.f/OUT_)-mean*mean;
  float rstd=rsqrtf(var+1e-6f);
  float nf=(v-mean)*rstd*g2v[t]+be2[t];
  size_t ro=(size_t)row*OUT_+t;
  node[ro]=nf;
  out2[ro]=nf + bf2f(o2bT[ro]);
}

extern "C" void kernel_launch(void* const* d_in, const int* in_sizes, int n_in,
                              void* d_out, int out_size, void* d_ws, size_t ws_size,
                              hipStream_t stream)
{
  const float* x    = (const float*)d_in[0];
  const float* m1   = (const float*)d_in[1];
  const float* m2   = (const float*)d_in[2];
  const float* sc   = (const float*)d_in[3];
  const float* gt   = (const float*)d_in[4];
  const float* Watt = (const float*)d_in[5];
  const float* batt = (const float*)d_in[6];
  const float* W1   = (const float*)d_in[7];
  const float* b1   = (const float*)d_in[8];
  const float* W2   = (const float*)d_in[9];
  const float* b2   = (const float*)d_in[10];
  const float* g1   = (const float*)d_in[11];
  const float* be1  = (const float*)d_in[12];
  const float* g2   = (const float*)d_in[13];
  const float* be2  = (const float*)d_in[14];
  const float* Wg   = (const float*)d_in[15];
  const float* bg   = (const float*)d_in[16];

  float* out2 = (float*)d_out;
  float* gtso = out2 + (size_t)B_*N_*OUT_;
  float* node = gtso + (size_t)B_*N_*OUT_;

  char* ws = (char*)d_ws;
  float*  colf = (float*)(ws);                 // 4 KB
  float*  lj   = (float*)(ws + 4096);          // 64 KB
  float*  li   = (float*)(ws + 69632);         // 64 KB
  ushort* W1b  = (ushort*)(ws + 135168);       // 64 KB
  ushort* W2b  = (ushort*)(ws + 200704);       // 64 KB
  ushort* WgTb = (ushort*)(ws + 266240);       // 128 KB
  // R1 (32 MB): mrs -> o1mT
  char* R1 = ws + 1048576;
  ushort* mrs  = (ushort*)R1;
  float*  o1mT = (float*)R1;
  // R2 (32 MB): Atb
  ushort* Atb  = (ushort*)(ws + 34603008);
  // R3 (16 MB): xb(8) | gtb(8)  ->  o2b(8) | o2bT(8)
  char* R3 = ws + 68157440;
  ushort* xb   = (ushort*)R3;
  ushort* gtb  = (ushort*)(R3 + 8388608);
  ushort* o2b  = (ushort*)R3;
  ushort* o2bT = (ushort*)(R3 + 8388608);
  // R4 (16 MB): o1b -> o1pb
  char* R4 = ws + 84934656;
  ushort* o1b  = (ushort*)R4;
  ushort* o1pb = (ushort*)R4;
  // R5 (16 MB): o1bT -> o2mT
  char* R5 = ws + 101711872;
  ushort* o1bT = (ushort*)R5;
  float*  o2mT = (float*)R5;

  hipMemsetAsync(colf, 0, 4096, stream);
  k_pc   <<<dim3(8192),dim3(256),0,stream>>>(x, gt, Watt, lj, li, xb, gtb);
  k_wcast<<<dim3(512),dim3(256),0,stream>>>(W1, W2, Wg, W1b, W2b, WgTb);
  k_col  <<<dim3(B_*N_),dim3(256),0,stream>>>(m1,m2,sc,lj,li,batt,colf,mrs);
  k_at   <<<dim3(B_*N_),dim3(256),0,stream>>>(mrs,sc,lj,li,batt,colf,Atb);

  // gts = relu(gt @ Wg + bg): M=16384, N=256, K=256
  mgemm<128,128,2,2,64><<<dim3(2,128,1),256,0,stream>>>(
      gtb, CIN_, 0,0,
      WgTb, CIN_, 0,0,
      gtso, (ushort*)0, OUT_, 0,0,
      (ushort*)0, 0,0,0,
      CIN_, 1, nullptr,0, bg, 1);

  // gconv1: per (b,g): o1b[b,128g+m,n]=relu(W1g.x); also o1bT[b,n,128g+m]
  mgemm<128,128,2,2,64><<<dim3(8,1,B_*4),256,0,stream>>>(
      W1b, 64, 0, (long long)128*64,
      xb, CIN_, (long long)N_*CIN_, 64,
      (float*)0, o1b, N_, (long long)MID_*N_, (long long)128*N_,
      o1bT, (long long)N_*MID_, 128, MID_,
      64, 4, b1, 128, nullptr, 1);

  // GEMM1: o1mT[b,i,m] = sum_j At[b,i,j]*o1[b,m,j]
  mgemm<128,128,2,2,64><<<dim3(4,8,B_),256,0,stream>>>(
      Atb, N_, (long long)N_*N_, 0,
      o1b, N_, (long long)MID_*N_, 0,
      o1mT, (ushort*)0, MID_, (long long)N_*MID_, 0,
      (ushort*)0, 0,0,0,
      N_, 1, nullptr,0, nullptr, 0);

  k_ln1<<<dim3(B_*N_),256,0,stream>>>(o1mT, o1bT, g1, be1, o1pb);

  // gconv2: per (b,g): o2b[b,64g+m,n]=relu(W2g.o1p); also o2bT[b,n,64g+m]
  mgemm<64,256,1,4,64><<<dim3(4,1,B_*4),256,0,stream>>>(
      W2b, 128, 0, (long long)64*128,
      o1pb, MID_, (long long)N_*MID_, 128,
      (float*)0, o2b, N_, (long long)OUT_*N_, (long long)64*N_,
      o2bT, (long long)N_*OUT_, 64, OUT_,
      128, 4, b2, 64, nullptr, 1);

  // GEMM2: o2mT[b,i,m] = sum_j At[b,i,j]*o2[b,m,j]
  mgemm<128,128,2,2,64><<<dim3(2,8,B_),256,0,stream>>>(
      Atb, N_, (long long)N_*N_, 0,
      o2b, N_, (long long)OUT_*N_, 0,
      o2mT, (ushort*)0, OUT_, (long long)N_*OUT_, 0,
      (ushort*)0, 0,0,0,
      N_, 1, nullptr,0, nullptr, 0);

  k_ln2f<<<dim3(B_*N_),256,0,stream>>>(o2mT, o2bT, g2, be2, node, out2);
}